// Round 7
// baseline (471.276 us; speedup 1.0000x reference)
//
#include <hip/hip_runtime.h>
#include <hip/hip_bf16.h>

// Problem constants
#define D_MODEL 2048
#define D_FF    8192
#define N_KV    256
#define S_TOP   16
#define M_ROWS  4096   // B*T = 4*1024

typedef __attribute__((ext_vector_type(8))) short bf16x8;   // 8 bf16 (4 VGPRs)
typedef __attribute__((ext_vector_type(4))) float f32x4;
typedef __hip_bfloat16 bf16;

typedef const __attribute__((address_space(1))) unsigned int* gp_t;
typedef __attribute__((address_space(3))) unsigned int* lp_t;

__device__ __forceinline__ void gload16(const void* g, void* l) {
  // async global->LDS, 16B per lane; LDS dest = wave-uniform base + lane*16
  __builtin_amdgcn_global_load_lds((gp_t)g, (lp_t)l, 16, 0, 0);
}

#define CFENCE asm volatile("" ::: "memory")

// ---------------- fused max|w| over the 4 weight tensors (blockIdx.y selects tensor) -------
__global__ __launch_bounds__(256) void maxabs4_kernel(const float4* __restrict__ w0, int n0,
                                                      const float4* __restrict__ w1, int n1,
                                                      const float4* __restrict__ w2, int n2,
                                                      const float4* __restrict__ w3, int n3,
                                                      unsigned* __restrict__ out) {
  const float4* w = blockIdx.y == 0 ? w0 : blockIdx.y == 1 ? w1 : blockIdx.y == 2 ? w2 : w3;
  int n4 = blockIdx.y == 0 ? n0 : blockIdx.y == 1 ? n1 : blockIdx.y == 2 ? n2 : n3;
  float m = 0.f;
  for (long i = (long)blockIdx.x * 256 + threadIdx.x; i < n4; i += (long)gridDim.x * 256) {
    float4 v = w[i];
    m = fmaxf(m, fmaxf(fmaxf(fabsf(v.x), fabsf(v.y)), fmaxf(fabsf(v.z), fabsf(v.w))));
  }
#pragma unroll
  for (int o = 32; o; o >>= 1) m = fmaxf(m, __shfl_down(m, o, 64));
  __shared__ float sm[4];
  int lane = threadIdx.x & 63, wid = threadIdx.x >> 6;
  if (lane == 0) sm[wid] = m;
  __syncthreads();
  if (threadIdx.x == 0) {
    float mm = fmaxf(fmaxf(sm[0], sm[1]), fmaxf(sm[2], sm[3]));
    atomicMax(out + blockIdx.y, __float_as_uint(mm));
  }
}

// ---------------- quantize + transpose: in [R][C] f32 -> out [C][R] ------------------------
__global__ __launch_bounds__(256) void quantT_f32(const float* __restrict__ in,
                                                  float* __restrict__ out, int R, int C,
                                                  const unsigned* __restrict__ maxbits) {
  __shared__ float tile[64][65];
  float scale = 127.f / fmaxf(__uint_as_float(*maxbits), 1e-8f);
  int r0 = blockIdx.y << 6, c0 = blockIdx.x << 6;
  int tx = threadIdx.x & 63, ty = threadIdx.x >> 6;
#pragma unroll
  for (int i = 0; i < 16; ++i) {
    int r = ty + (i << 2);
    float v = in[(long)(r0 + r) * C + c0 + tx];
    tile[r][tx] = fminf(fmaxf(rintf(v * scale), -128.f), 127.f);
  }
  __syncthreads();
#pragma unroll
  for (int i = 0; i < 16; ++i) {
    int c = ty + (i << 2);
    out[(long)(c0 + c) * R + r0 + tx] = tile[tx][c] / scale;
  }
}

// bf16 variant stores the INTEGER code (exact in bf16, |q|<=128); scale folded into epilogue.
__global__ __launch_bounds__(256) void quantT_bf16(const float* __restrict__ in,
                                                   bf16* __restrict__ out, int R, int C,
                                                   const unsigned* __restrict__ maxbits) {
  __shared__ float tile[64][65];
  float scale = 127.f / fmaxf(__uint_as_float(*maxbits), 1e-8f);
  int r0 = blockIdx.y << 6, c0 = blockIdx.x << 6;
  int tx = threadIdx.x & 63, ty = threadIdx.x >> 6;
#pragma unroll
  for (int i = 0; i < 16; ++i) {
    int r = ty + (i << 2);
    float v = in[(long)(r0 + r) * C + c0 + tx];
    tile[r][tx] = fminf(fmaxf(rintf(v * scale), -128.f), 127.f);
  }
  __syncthreads();
#pragma unroll
  for (int i = 0; i < 16; ++i) {
    int c = ty + (i << 2);
    out[(long)(c0 + c) * R + r0 + tx] = __float2bfloat16(tile[tx][c]);
  }
}

// ---------------- gather-attention: one block per (b,t) ------------------------------------
__global__ __launch_bounds__(256) void attn_kernel(const float* __restrict__ x,
                                                   const int* __restrict__ idx,
                                                   const float* __restrict__ KqT,
                                                   const float* __restrict__ VqT,
                                                   bf16* __restrict__ combHi) {
  int bt = blockIdx.x;
  const float* xr = x + (long)bt * D_MODEL;
  __shared__ int sidx[S_TOP];
  __shared__ float sred[S_TOP][4];
  __shared__ float sp[S_TOP];
  int t = threadIdx.x, lane = t & 63, wid = t >> 6;
  if (t < S_TOP) sidx[t] = idx[(long)bt * S_TOP + t];
  __syncthreads();
  float xv[8];
#pragma unroll
  for (int j = 0; j < 8; ++j) xv[j] = xr[t + (j << 8)];
#pragma unroll
  for (int s = 0; s < S_TOP; ++s) {
    const float* kc = KqT + (long)sidx[s] * D_MODEL;
    float a = 0.f;
#pragma unroll
    for (int j = 0; j < 8; ++j) a += xv[j] * kc[t + (j << 8)];
#pragma unroll
    for (int o = 32; o; o >>= 1) a += __shfl_down(a, o, 64);
    if (lane == 0) sred[s][wid] = a;
  }
  __syncthreads();
  if (t < S_TOP) {
    float sc = sred[t][0] + sred[t][1] + sred[t][2] + sred[t][3];
    float mx = sc;
#pragma unroll
    for (int o = 8; o; o >>= 1) mx = fmaxf(mx, __shfl_xor(mx, o, 16));
    float e = __expf(sc - mx);
    float su = e;
#pragma unroll
    for (int o = 8; o; o >>= 1) su += __shfl_xor(su, o, 16);
    sp[t] = e / su;
  }
  __syncthreads();
  float p[S_TOP];
#pragma unroll
  for (int s = 0; s < S_TOP; ++s) p[s] = sp[s];
#pragma unroll
  for (int j = 0; j < 8; ++j) {
    int d = t + (j << 8);
    float c = 0.f;
#pragma unroll
    for (int s = 0; s < S_TOP; ++s) c += p[s] * VqT[(long)sidx[s] * D_MODEL + d];
    combHi[(long)bt * D_MODEL + d] = __float2bfloat16(c);
  }
}

// ---------------- 256x256 8-wave GEMM, phase-pair schedule + region-freeing prefetch -------
// C[M][N] = A @ B^T * (max/127).  A: [M][KT] bf16 acts, B: [N][KT] bf16 integer codes.
// BK=64, ping-pong LDS (buf c = j&1). Region-freeing deep prefetch: within tile j's phases,
// B-region of buf c is fully read after P2, A-region after P3 -> stage tile j+2's B halves
// at P3 and A halves at P4 INTO BUF c (barrier-separated). Issue->use distance for any
// staged load is 5-6 phases, so the per-tile vmcnt(8) (8 = tile j+2's in-flight loads)
// never stalls yet PROVES tile j+1 landed before its P1 reads. Phases:
//  P1: ds 12 (aF m0-3, bF n0-1);              barrier; prio1; q1 MFMA x16; prio0
//  P2: ds 4  (bF n2-3);                                prio1; q2 MFMA x16; prio0; barrier
//  P3: ds 8  (aF m4-7); stage B'(j+2)->buf c; barrier; prio1; q3 MFMA x16; prio0; barrier
//  P4: stage A'(j+2)->buf c; vmcnt(8);        barrier; prio1; q4 MFMA x16; prio0
// LDS bank swizzle: byte_col ^= (row&7)<<4 via pre-swizzled global source col + swizzled
// ds_read (both-sides rule); measured conflict-free (r5: SQ_LDS_BANK_CONFLICT = 0).
// SPLITK: gridDim.z=2, halves atomicAdd f32 into zeroed out (2 addends -> deterministic).
template <int KT, bool SPLITK, typename OutT>
__global__ __launch_bounds__(512, 2) void gemm8(const bf16* __restrict__ A,
                                                const bf16* __restrict__ B,
                                                const unsigned* maxbits,
                                                OutT* __restrict__ out, int Ntot) {
  __shared__ char lds[131072];  // A: [2][256][64] @0 (64KB), B: same @65536
  const int t = threadIdx.x, lane = t & 63, wid = t >> 6;
  const int wr = wid >> 2, wc = wid & 3;            // wave grid 2M x 4N
  // bijective XCD swizzle over (x,y); nwg % 8 == 0 for all our grids
  const int gx = gridDim.x, nwg = gx * gridDim.y;
  const int bid = blockIdx.y * gx + blockIdx.x;
  const int swz = (bid & 7) * (nwg >> 3) + (bid >> 3);
  const long m0 = (long)(swz / gx) << 8;
  const long n0 = (long)(swz % gx) << 8;
  const int NT = (SPLITK ? KT / 2 : KT) / 64;
  const bf16* gA = A + m0 * KT + (SPLITK ? blockIdx.z * (KT / 2) : 0);
  const bf16* gB = B + n0 * KT + (SPLITK ? blockIdx.z * (KT / 2) : 0);

  // staging: thread t covers row srow=t>>3, 16B slot (t&7); source col inverse-swizzled
  const int srow = t >> 3;                           // 0..63 per gload round
  const int gcol = ((t & 7) ^ (srow & 7)) << 3;      // elements (bytes>>1)
  // frag reads: byte col ^= (row&7)<<4; row&7 == lane&7 (all row bases are mult of 16)
  const int xr = (lane & 7) << 4;
  const int arow = lane & 15;
  const int kcolb = (lane >> 4) << 4;                // 0,16,32,48 bytes

  f32x4 acc[8][4] = {};

#define STAGE(mat, h, j, c)                                                          \
  {                                                                                  \
    const bf16* _g = (mat ? gB : gA) + (long)((h)*128) * KT + (long)(j)*64 + gcol;   \
    char* _l = lds + (mat)*65536 + (c)*32768 + (h)*16384;                            \
    gload16(_g + (long)srow * KT, _l + (t << 4));                                    \
    gload16(_g + (long)(64 + srow) * KT, _l + 8192 + (t << 4));                      \
  }

  // prologue: tile 0 -> buf 0, tile 1 -> buf 1 (8 loads each)
  STAGE(0, 0, 0, 0) STAGE(0, 1, 0, 0) STAGE(1, 0, 0, 0) STAGE(1, 1, 0, 0)
  STAGE(0, 0, 1, 1) STAGE(0, 1, 1, 1) STAGE(1, 0, 1, 1) STAGE(1, 1, 1, 1)
  asm volatile("s_waitcnt vmcnt(8)" ::: "memory");  // tile 0 landed; tile 1 in flight
  __builtin_amdgcn_s_barrier();

  bf16x8 aF[4][2], bF[4][2];

  for (int j = 0; j < NT; ++j) {
    const int c = j & 1;
    const char* lA = lds + c * 32768;
    const char* lB = lds + 65536 + c * 32768;
    // ---- P1: ds aF m0-3 + bF n0-1 (12 reads)
#pragma unroll
    for (int m = 0; m < 4; ++m)
#pragma unroll
      for (int ks = 0; ks < 2; ++ks)
        aF[m][ks] = *(const bf16x8*)(lA + (wr * 128 + m * 16 + arow) * 128 +
                                     ((ks * 64 + kcolb) ^ xr));
#pragma unroll
    for (int n = 0; n < 2; ++n)
#pragma unroll
      for (int ks = 0; ks < 2; ++ks)
        bF[n][ks] = *(const bf16x8*)(lB + (wc * 64 + n * 16 + arow) * 128 +
                                     ((ks * 64 + kcolb) ^ xr));
    CFENCE; __builtin_amdgcn_s_barrier(); CFENCE;
    __builtin_amdgcn_s_setprio(1);
#pragma unroll
    for (int m = 0; m < 4; ++m)
#pragma unroll
      for (int n = 0; n < 2; ++n)
#pragma unroll
        for (int ks = 0; ks < 2; ++ks)
          acc[m][n] = __builtin_amdgcn_mfma_f32_16x16x32_bf16(aF[m][ks], bF[n][ks], acc[m][n], 0, 0, 0);
    __builtin_amdgcn_s_setprio(0);
    // ---- P2: ds bF n2-3 (4 reads); q2
#pragma unroll
    for (int n = 0; n < 2; ++n)
#pragma unroll
      for (int ks = 0; ks < 2; ++ks)
        bF[2 + n][ks] = *(const bf16x8*)(lB + (wc * 64 + (2 + n) * 16 + arow) * 128 +
                                         ((ks * 64 + kcolb) ^ xr));
    __builtin_amdgcn_s_setprio(1);
#pragma unroll
    for (int m = 0; m < 4; ++m)
#pragma unroll
      for (int n = 0; n < 2; ++n)
#pragma unroll
        for (int ks = 0; ks < 2; ++ks)
          acc[m][2 + n] = __builtin_amdgcn_mfma_f32_16x16x32_bf16(aF[m][ks], bF[2 + n][ks], acc[m][2 + n], 0, 0, 0);
    __builtin_amdgcn_s_setprio(0);
    CFENCE; __builtin_amdgcn_s_barrier(); CFENCE;  // retire ALL B reads of buf c
    // ---- P3: ds aF m4-7 (8 reads); stage tile j+2's B halves into buf c B-region
#pragma unroll
    for (int m = 0; m < 4; ++m)
#pragma unroll
      for (int ks = 0; ks < 2; ++ks)
        aF[m][ks] = *(const bf16x8*)(lA + (wr * 128 + (4 + m) * 16 + arow) * 128 +
                                     ((ks * 64 + kcolb) ^ xr));
    if (j + 2 < NT) { STAGE(1, 0, j + 2, c) STAGE(1, 1, j + 2, c) }
    CFENCE; __builtin_amdgcn_s_barrier(); CFENCE;
    __builtin_amdgcn_s_setprio(1);
#pragma unroll
    for (int m = 0; m < 4; ++m)
#pragma unroll
      for (int n = 0; n < 2; ++n)
#pragma unroll
        for (int ks = 0; ks < 2; ++ks)
          acc[4 + m][n] = __builtin_amdgcn_mfma_f32_16x16x32_bf16(aF[m][ks], bF[n][ks], acc[4 + m][n], 0, 0, 0);
    __builtin_amdgcn_s_setprio(0);
    CFENCE; __builtin_amdgcn_s_barrier(); CFENCE;  // retire ALL A reads of buf c
    // ---- P4: stage tile j+2's A halves into buf c A-region; prove tile j+1 landed
    if (j + 2 < NT) {
      STAGE(0, 0, j + 2, c) STAGE(0, 1, j + 2, c)
      asm volatile("s_waitcnt vmcnt(8)" ::: "memory");  // older than j+2's 8 => j+1 landed
    } else {
      asm volatile("s_waitcnt vmcnt(0)" ::: "memory");  // tail: cheap, loads are old
    }
    __builtin_amdgcn_s_barrier();
    __builtin_amdgcn_s_setprio(1);
#pragma unroll
    for (int m = 0; m < 4; ++m)
#pragma unroll
      for (int n = 0; n < 2; ++n)
#pragma unroll
        for (int ks = 0; ks < 2; ++ks)
          acc[4 + m][2 + n] = __builtin_amdgcn_mfma_f32_16x16x32_bf16(aF[m][ks], bF[2 + n][ks], acc[4 + m][2 + n], 0, 0, 0);
    __builtin_amdgcn_s_setprio(0);
  }
#undef STAGE

  // volatile AFTER the loop: keeps this VMEM op out of the pipelined region
  float inv = fmaxf(__uint_as_float(*(volatile const unsigned*)maxbits), 1e-8f) * (1.f / 127.f);
#pragma unroll
  for (int m = 0; m < 8; ++m)
#pragma unroll
    for (int n = 0; n < 4; ++n)
#pragma unroll
      for (int r = 0; r < 4; ++r) {
        long row = m0 + wr * 128 + m * 16 + ((lane >> 4) << 2) + r;  // C/D: row=(lane>>4)*4+reg
        long col = n0 + wc * 64 + n * 16 + (lane & 15);              //      col=lane&15
        float h = acc[m][n][r] * inv;
        if constexpr (SPLITK)
          atomicAdd(&out[row * Ntot + col], h);
        else if constexpr (__is_same(OutT, float))
          out[row * Ntot + col] = h;
        else
          out[row * Ntot + col] = __float2bfloat16(h);
      }
}

extern "C" void kernel_launch(void* const* d_in, const int* in_sizes, int n_in, void* d_out,
                              int out_size, void* d_ws, size_t ws_size, hipStream_t stream) {
  const float* x = (const float*)d_in[0];
  const int* idx = (const int*)d_in[1];
  const float* W_K = (const float*)d_in[2];
  const float* W_V = (const float*)d_in[3];
  const float* W_in = (const float*)d_in[4];
  const float* W_out = (const float*)d_in[5];
  float* out = (float*)d_out;  // reference output dtype is float32

  char* ws = (char*)d_ws;
  size_t off = 0;
  unsigned* maxb = (unsigned*)(ws + off); off += 256;
  float* KqT = (float*)(ws + off); off += (size_t)N_KV * D_MODEL * 4;   // [256][2048] f32
  float* VqT = (float*)(ws + off); off += (size_t)N_KV * D_MODEL * 4;
  bf16* QinT = (bf16*)(ws + off); off += (size_t)D_FF * D_MODEL * 2;    // [8192][2048]
  // comb region; QoutT overlays it after GEMM1 (comb dead by then)
  bf16* combHi = (bf16*)(ws + off);
  bf16* QoutT = (bf16*)(ws + off);
  off += (size_t)D_MODEL * D_FF * 2;  // 33.5 MB ([2048][8192])
  bf16* hidHi = (bf16*)(ws + off); off += (size_t)M_ROWS * D_FF * 2;    // 67 MB

  hipMemsetAsync(maxb, 0, 16, stream);
  hipMemsetAsync(out, 0, (size_t)M_ROWS * D_MODEL * 4, stream);  // split-K atomic target
  maxabs4_kernel<<<dim3(512, 4), 256, 0, stream>>>(
      (const float4*)W_K, (D_MODEL * N_KV) / 4, (const float4*)W_V, (D_MODEL * N_KV) / 4,
      (const float4*)W_in, (D_MODEL * D_FF) / 4, (const float4*)W_out, (D_FF * D_MODEL) / 4,
      maxb);

  quantT_f32<<<dim3(N_KV / 64, D_MODEL / 64), 256, 0, stream>>>(W_K, KqT, D_MODEL, N_KV, maxb + 0);
  quantT_f32<<<dim3(N_KV / 64, D_MODEL / 64), 256, 0, stream>>>(W_V, VqT, D_MODEL, N_KV, maxb + 1);
  quantT_bf16<<<dim3(D_FF / 64, D_MODEL / 64), 256, 0, stream>>>(W_in, QinT, D_MODEL, D_FF, maxb + 2);

  attn_kernel<<<M_ROWS, 256, 0, stream>>>(x, idx, KqT, VqT, combHi);

  gemm8<D_MODEL, false, bf16><<<dim3(D_FF / 256, M_ROWS / 256), 512, 0, stream>>>(
      combHi, QinT, maxb + 2, hidHi, D_FF);

  quantT_bf16<<<dim3(D_MODEL / 64, D_FF / 64), 256, 0, stream>>>(W_out, QoutT, D_FF, D_MODEL, maxb + 3);

  gemm8<D_FF, true, float><<<dim3(D_MODEL / 256, M_ROWS / 256, 2), 512, 0, stream>>>(
      hidHi, QoutT, maxb + 3, out, D_MODEL);
}

// Round 9
// 464.326 us; speedup vs baseline: 1.0150x; 1.0150x over previous
//
#include <hip/hip_runtime.h>
#include <hip/hip_bf16.h>

// Problem constants
#define D_MODEL 2048
#define D_FF    8192
#define N_KV    256
#define S_TOP   16
#define M_ROWS  4096   // B*T = 4*1024

typedef __attribute__((ext_vector_type(8))) short bf16x8;   // 8 bf16 (4 VGPRs)
typedef __attribute__((ext_vector_type(4))) float f32x4;
typedef __hip_bfloat16 bf16;

typedef const __attribute__((address_space(1))) unsigned int* gp_t;
typedef __attribute__((address_space(3))) unsigned int* lp_t;

__device__ __forceinline__ void gload16(const void* g, void* l) {
  // async global->LDS, 16B per lane; LDS dest = wave-uniform base + lane*16
  __builtin_amdgcn_global_load_lds((gp_t)g, (lp_t)l, 16, 0, 0);
}

#define CFENCE asm volatile("" ::: "memory")

// ---------------- fused max|w| over the 4 weight tensors (blockIdx.y selects tensor) -------
__global__ __launch_bounds__(256) void maxabs4_kernel(const float4* __restrict__ w0, int n0,
                                                      const float4* __restrict__ w1, int n1,
                                                      const float4* __restrict__ w2, int n2,
                                                      const float4* __restrict__ w3, int n3,
                                                      unsigned* __restrict__ out) {
  const float4* w = blockIdx.y == 0 ? w0 : blockIdx.y == 1 ? w1 : blockIdx.y == 2 ? w2 : w3;
  int n4 = blockIdx.y == 0 ? n0 : blockIdx.y == 1 ? n1 : blockIdx.y == 2 ? n2 : n3;
  float m = 0.f;
  for (long i = (long)blockIdx.x * 256 + threadIdx.x; i < n4; i += (long)gridDim.x * 256) {
    float4 v = w[i];
    m = fmaxf(m, fmaxf(fmaxf(fabsf(v.x), fabsf(v.y)), fmaxf(fabsf(v.z), fabsf(v.w))));
  }
#pragma unroll
  for (int o = 32; o; o >>= 1) m = fmaxf(m, __shfl_down(m, o, 64));
  __shared__ float sm[4];
  int lane = threadIdx.x & 63, wid = threadIdx.x >> 6;
  if (lane == 0) sm[wid] = m;
  __syncthreads();
  if (threadIdx.x == 0) {
    float mm = fmaxf(fmaxf(sm[0], sm[1]), fmaxf(sm[2], sm[3]));
    atomicMax(out + blockIdx.y, __float_as_uint(mm));
  }
}

// ---------------- quantize + transpose: in [R][C] f32 -> out [C][R] ------------------------
__global__ __launch_bounds__(256) void quantT_f32(const float* __restrict__ in,
                                                  float* __restrict__ out, int R, int C,
                                                  const unsigned* __restrict__ maxbits) {
  __shared__ float tile[64][65];
  float scale = 127.f / fmaxf(__uint_as_float(*maxbits), 1e-8f);
  int r0 = blockIdx.y << 6, c0 = blockIdx.x << 6;
  int tx = threadIdx.x & 63, ty = threadIdx.x >> 6;
#pragma unroll
  for (int i = 0; i < 16; ++i) {
    int r = ty + (i << 2);
    float v = in[(long)(r0 + r) * C + c0 + tx];
    tile[r][tx] = fminf(fmaxf(rintf(v * scale), -128.f), 127.f);
  }
  __syncthreads();
#pragma unroll
  for (int i = 0; i < 16; ++i) {
    int c = ty + (i << 2);
    out[(long)(c0 + c) * R + r0 + tx] = tile[tx][c] / scale;
  }
}

// bf16 variant stores the INTEGER code (exact in bf16, |q|<=128); scale folded into epilogue.
__global__ __launch_bounds__(256) void quantT_bf16(const float* __restrict__ in,
                                                   bf16* __restrict__ out, int R, int C,
                                                   const unsigned* __restrict__ maxbits) {
  __shared__ float tile[64][65];
  float scale = 127.f / fmaxf(__uint_as_float(*maxbits), 1e-8f);
  int r0 = blockIdx.y << 6, c0 = blockIdx.x << 6;
  int tx = threadIdx.x & 63, ty = threadIdx.x >> 6;
#pragma unroll
  for (int i = 0; i < 16; ++i) {
    int r = ty + (i << 2);
    float v = in[(long)(r0 + r) * C + c0 + tx];
    tile[r][tx] = fminf(fmaxf(rintf(v * scale), -128.f), 127.f);
  }
  __syncthreads();
#pragma unroll
  for (int i = 0; i < 16; ++i) {
    int c = ty + (i << 2);
    out[(long)(c0 + c) * R + r0 + tx] = __float2bfloat16(tile[tx][c]);
  }
}

// ---------------- gather-attention: one block per (b,t) ------------------------------------
__global__ __launch_bounds__(256) void attn_kernel(const float* __restrict__ x,
                                                   const int* __restrict__ idx,
                                                   const float* __restrict__ KqT,
                                                   const float* __restrict__ VqT,
                                                   bf16* __restrict__ combHi) {
  int bt = blockIdx.x;
  const float* xr = x + (long)bt * D_MODEL;
  __shared__ int sidx[S_TOP];
  __shared__ float sred[S_TOP][4];
  __shared__ float sp[S_TOP];
  int t = threadIdx.x, lane = t & 63, wid = t >> 6;
  if (t < S_TOP) sidx[t] = idx[(long)bt * S_TOP + t];
  __syncthreads();
  float xv[8];
#pragma unroll
  for (int j = 0; j < 8; ++j) xv[j] = xr[t + (j << 8)];
#pragma unroll
  for (int s = 0; s < S_TOP; ++s) {
    const float* kc = KqT + (long)sidx[s] * D_MODEL;
    float a = 0.f;
#pragma unroll
    for (int j = 0; j < 8; ++j) a += xv[j] * kc[t + (j << 8)];
#pragma unroll
    for (int o = 32; o; o >>= 1) a += __shfl_down(a, o, 64);
    if (lane == 0) sred[s][wid] = a;
  }
  __syncthreads();
  if (t < S_TOP) {
    float sc = sred[t][0] + sred[t][1] + sred[t][2] + sred[t][3];
    float mx = sc;
#pragma unroll
    for (int o = 8; o; o >>= 1) mx = fmaxf(mx, __shfl_xor(mx, o, 16));
    float e = __expf(sc - mx);
    float su = e;
#pragma unroll
    for (int o = 8; o; o >>= 1) su += __shfl_xor(su, o, 16);
    sp[t] = e / su;
  }
  __syncthreads();
  float p[S_TOP];
#pragma unroll
  for (int s = 0; s < S_TOP; ++s) p[s] = sp[s];
#pragma unroll
  for (int j = 0; j < 8; ++j) {
    int d = t + (j << 8);
    float c = 0.f;
#pragma unroll
    for (int s = 0; s < S_TOP; ++s) c += p[s] * VqT[(long)sidx[s] * D_MODEL + d];
    combHi[(long)bt * D_MODEL + d] = __float2bfloat16(c);
  }
}

// ---------------- 256x256 8-wave GEMM: faithful 8-phase/2-K-tile m201 schedule -------------
// C[M][N] = A @ B^T * (max/127).  A: [M][KT] bf16 acts, B: [N][KT] bf16 integer codes.
// KEY: interleaved wave mapping rows = m*32 + wr*16, cols = n*64 + wc*16 so each quadrant
// touches ONE A-half x ONE B-half across ALL waves:
//   Q1=A0xB0 (12 ds_reads) Q2=A0xB1 (4) Q3=A1xB0 (8) Q4=A1xB1 (0)  [reg reuse]
// Half free points (block-wide, via end-of-phase barrier): A0,B0 after P1; B1 after P2;
// A1 after P3. One half-tile staged per phase, >=1 barrier between last read and stage:
//   Ph1: B1'(T+1)->buf1   Ph2: A0'(T+2)->buf0  Ph3: B0'(T+2)  Ph4: A1'(T+2) + vmcnt(6)
//   Ph5: B1'(T+2)         Ph6: A0'(T+3)->buf1  Ph7: B0'(T+3)  Ph8: A1'(T+3) + vmcnt(6)
// FIFO ledger: entering Ph1 outstanding = 6 {A0',B0',A1' of T+1}; Ph4's vmcnt(6) retires
// exactly T+1's 8 loads (proves it before Ph5); Ph8's retires T+2's 8 (before next Ph1).
// Last iteration (T+2>=NT): stages guarded out, waits become vmcnt(0).
// Phase body: {ds_reads; stage; [lgkm(8) if 12 reads]; barrier; lgkm(0); sched_barrier;
//              setprio(1); 16 MFMA; setprio(0); barrier}
// LDS swizzle: byte_col ^= (row&7)<<4 both-sides (r5/r6: SQ_LDS_BANK_CONFLICT == 0).
// SPLITK: gridDim.z=2, halves atomicAdd f32 into zeroed out (2 addends -> deterministic).
template <int KT, bool SPLITK, typename OutT>
__global__ __launch_bounds__(512, 2) void gemm8(const bf16* __restrict__ A,
                                                const bf16* __restrict__ B,
                                                const unsigned* maxbits,
                                                OutT* __restrict__ out, int Ntot) {
  __shared__ char lds[131072];  // A: [buf][half][128][64] @0 (64KB); B same @65536
  const int t = threadIdx.x, lane = t & 63, wid = t >> 6;
  const int wr = wid >> 2, wc = wid & 3;            // wave grid 2M x 4N (interleaved tiles)
  // bijective XCD swizzle over (x,y); nwg % 8 == 0 for all our grids
  const int gx = gridDim.x, nwg = gx * gridDim.y;
  const int bid = blockIdx.y * gx + blockIdx.x;
  const int swz = (bid & 7) * (nwg >> 3) + (bid >> 3);
  const long m0 = (long)(swz / gx) << 8;
  const long n0 = (long)(swz % gx) << 8;
  const int NT = (SPLITK ? KT / 2 : KT) / 64;       // even for all our shapes
  const bf16* gA = A + m0 * KT + (SPLITK ? blockIdx.z * (KT / 2) : 0);
  const bf16* gB = B + n0 * KT + (SPLITK ? blockIdx.z * (KT / 2) : 0);

  // staging: thread t covers row srow=t>>3, 16B slot (t&7); source col inverse-swizzled
  const int srow = t >> 3;
  const int gcol = ((t & 7) ^ (srow & 7)) << 3;      // elements
  // frag reads: byte col ^= (row&7)<<4; row&7 == lane&7 (row bases are multiples of 16)
  const int xr = (lane & 7) << 4;
  const int arow = lane & 15;
  const int kcolb = (lane >> 4) << 4;                // 0,16,32,48 bytes

  f32x4 acc[8][4] = {};

#define STAGE(mat, h, j, c)                                                          \
  {                                                                                  \
    const bf16* _g = (mat ? gB : gA) + (long)((h)*128) * KT + (long)(j)*64 + gcol;   \
    char* _l = lds + (mat)*65536 + (c)*32768 + (h)*16384;                            \
    gload16(_g + (long)srow * KT, _l + (t << 4));                                    \
    gload16(_g + (long)(64 + srow) * KT, _l + 8192 + (t << 4));                      \
  }
// A frag read: half h, m-frag mf(0-3), k-slice ks
#define LDA(buf, h, mf, ks)                                                          \
  (*(const bf16x8*)(lds + (buf)*32768 + (h)*16384 +                                  \
                    ((mf)*32 + wr * 16 + arow) * 128 + (((ks)*64 + kcolb) ^ xr)))
#define LDB(buf, h, nf, ks)                                                          \
  (*(const bf16x8*)(lds + 65536 + (buf)*32768 + (h)*16384 +                          \
                    ((nf)*64 + wc * 16 + arow) * 128 + (((ks)*64 + kcolb) ^ xr)))
#define MFMA_Q(AF, BF, ro, co)                                                       \
  _Pragma("unroll") for (int m = 0; m < 4; ++m)                                      \
  _Pragma("unroll") for (int n = 0; n < 2; ++n)                                      \
  _Pragma("unroll") for (int ks = 0; ks < 2; ++ks)                                   \
    acc[(ro) + m][(co) + n] =                                                        \
        __builtin_amdgcn_mfma_f32_16x16x32_bf16(AF[m][ks], BF[n][ks], acc[(ro) + m][(co) + n], 0, 0, 0);
#define PH_SYNC                                                                      \
  CFENCE; __builtin_amdgcn_s_barrier();                                              \
  asm volatile("s_waitcnt lgkmcnt(0)" ::: "memory");                                 \
  __builtin_amdgcn_sched_barrier(0);
#define PH_END CFENCE; __builtin_amdgcn_s_barrier(); CFENCE;

  // prologue: tile0 full -> buf0 (8 loads), tile1 A0,B0,A1 -> buf1 (6 loads)
  STAGE(0, 0, 0, 0) STAGE(1, 0, 0, 0) STAGE(0, 1, 0, 0) STAGE(1, 1, 0, 0)
  STAGE(0, 0, 1, 1) STAGE(1, 0, 1, 1) STAGE(0, 1, 1, 1)
  asm volatile("s_waitcnt vmcnt(6)" ::: "memory");  // tile0 landed; tile1 partial in flight
  __builtin_amdgcn_s_barrier();

  bf16x8 aF[4][2], b0F[2][2], b1F[2][2];

  for (int T = 0; T < NT; T += 2) {
    const bool last = (T + 2 >= NT);
    // ======== Ph1: Q1 of T (buf0, A0xB0): 12 reads; stage B1'(T+1)->buf1 ========
#pragma unroll
    for (int m = 0; m < 4; ++m)
#pragma unroll
      for (int ks = 0; ks < 2; ++ks) aF[m][ks] = LDA(0, 0, m, ks);
#pragma unroll
    for (int n = 0; n < 2; ++n)
#pragma unroll
      for (int ks = 0; ks < 2; ++ks) b0F[n][ks] = LDB(0, 0, n, ks);
    STAGE(1, 1, T + 1, 1)
    asm volatile("s_waitcnt lgkmcnt(8)" ::: "memory");
    PH_SYNC
    __builtin_amdgcn_s_setprio(1);
    MFMA_Q(aF, b0F, 0, 0)
    __builtin_amdgcn_s_setprio(0);
    PH_END
    // ======== Ph2: Q2 (A0xB1): 4 reads; stage A0'(T+2)->buf0 ========
#pragma unroll
    for (int n = 0; n < 2; ++n)
#pragma unroll
      for (int ks = 0; ks < 2; ++ks) b1F[n][ks] = LDB(0, 1, n, ks);
    if (!last) STAGE(0, 0, T + 2, 0)
    PH_SYNC
    __builtin_amdgcn_s_setprio(1);
    MFMA_Q(aF, b1F, 0, 2)
    __builtin_amdgcn_s_setprio(0);
    PH_END
    // ======== Ph3: Q3 (A1xB0): 8 reads (aF overwritten); stage B0'(T+2) ========
#pragma unroll
    for (int m = 0; m < 4; ++m)
#pragma unroll
      for (int ks = 0; ks < 2; ++ks) aF[m][ks] = LDA(0, 1, m, ks);
    if (!last) STAGE(1, 0, T + 2, 0)
    PH_SYNC
    __builtin_amdgcn_s_setprio(1);
    MFMA_Q(aF, b0F, 4, 0)
    __builtin_amdgcn_s_setprio(0);
    PH_END
    // ======== Ph4: Q4 (A1xB1): 0 reads; stage A1'(T+2); vmcnt proves T+1 ========
    if (!last) {
      STAGE(0, 1, T + 2, 0)
      asm volatile("s_waitcnt vmcnt(6)" ::: "memory");
    } else {
      asm volatile("s_waitcnt vmcnt(0)" ::: "memory");
    }
    __builtin_amdgcn_s_barrier();
    __builtin_amdgcn_s_setprio(1);
    MFMA_Q(aF, b1F, 4, 2)
    __builtin_amdgcn_s_setprio(0);
    PH_END
    // ======== Ph5: Q1 of T+1 (buf1): 12 reads; stage B1'(T+2)->buf0 ========
#pragma unroll
    for (int m = 0; m < 4; ++m)
#pragma unroll
      for (int ks = 0; ks < 2; ++ks) aF[m][ks] = LDA(1, 0, m, ks);
#pragma unroll
    for (int n = 0; n < 2; ++n)
#pragma unroll
      for (int ks = 0; ks < 2; ++ks) b0F[n][ks] = LDB(1, 0, n, ks);
    if (!last) STAGE(1, 1, T + 2, 0)
    asm volatile("s_waitcnt lgkmcnt(8)" ::: "memory");
    PH_SYNC
    __builtin_amdgcn_s_setprio(1);
    MFMA_Q(aF, b0F, 0, 0)
    __builtin_amdgcn_s_setprio(0);
    PH_END
    // ======== Ph6: Q2: 4 reads; stage A0'(T+3)->buf1 ========
#pragma unroll
    for (int n = 0; n < 2; ++n)
#pragma unroll
      for (int ks = 0; ks < 2; ++ks) b1F[n][ks] = LDB(1, 1, n, ks);
    if (!last) STAGE(0, 0, T + 3, 1)
    PH_SYNC
    __builtin_amdgcn_s_setprio(1);
    MFMA_Q(aF, b1F, 0, 2)
    __builtin_amdgcn_s_setprio(0);
    PH_END
    // ======== Ph7: Q3: 8 reads; stage B0'(T+3) ========
#pragma unroll
    for (int m = 0; m < 4; ++m)
#pragma unroll
      for (int ks = 0; ks < 2; ++ks) aF[m][ks] = LDA(1, 1, m, ks);
    if (!last) STAGE(1, 0, T + 3, 1)
    PH_SYNC
    __builtin_amdgcn_s_setprio(1);
    MFMA_Q(aF, b0F, 4, 0)
    __builtin_amdgcn_s_setprio(0);
    PH_END
    // ======== Ph8: Q4: 0 reads; stage A1'(T+3); vmcnt proves T+2 ========
    if (!last) {
      STAGE(0, 1, T + 3, 1)
      asm volatile("s_waitcnt vmcnt(6)" ::: "memory");
    } else {
      asm volatile("s_waitcnt vmcnt(0)" ::: "memory");
    }
    __builtin_amdgcn_s_barrier();
    __builtin_amdgcn_s_setprio(1);
    MFMA_Q(aF, b1F, 4, 2)
    __builtin_amdgcn_s_setprio(0);
    PH_END
  }
#undef STAGE
#undef LDA
#undef LDB
#undef MFMA_Q
#undef PH_SYNC
#undef PH_END

  // volatile AFTER the loop: keeps this VMEM op out of the pipelined region
  float inv = fmaxf(__uint_as_float(*(volatile const unsigned*)maxbits), 1e-8f) * (1.f / 127.f);
#pragma unroll
  for (int m = 0; m < 8; ++m)
#pragma unroll
    for (int n = 0; n < 4; ++n)
#pragma unroll
      for (int r = 0; r < 4; ++r) {
        // interleaved wave mapping: row = (m&3)*32 + (m>>2)*128 + wr*16; col analog
        long row = m0 + (m & 3) * 32 + (m >> 2) * 128 + wr * 16 + ((lane >> 4) << 2) + r;
        long col = n0 + (n & 1) * 64 + (n >> 1) * 128 + wc * 16 + (lane & 15);
        float h = acc[m][n][r] * inv;
        if constexpr (SPLITK)
          atomicAdd(&out[row * Ntot + col], h);
        else if constexpr (__is_same(OutT, float))
          out[row * Ntot + col] = h;
        else
          out[row * Ntot + col] = __float2bfloat16(h);
      }
}

extern "C" void kernel_launch(void* const* d_in, const int* in_sizes, int n_in, void* d_out,
                              int out_size, void* d_ws, size_t ws_size, hipStream_t stream) {
  const float* x = (const float*)d_in[0];
  const int* idx = (const int*)d_in[1];
  const float* W_K = (const float*)d_in[2];
  const float* W_V = (const float*)d_in[3];
  const float* W_in = (const float*)d_in[4];
  const float* W_out = (const float*)d_in[5];
  float* out = (float*)d_out;  // reference output dtype is float32

  char* ws = (char*)d_ws;
  size_t off = 0;
  unsigned* maxb = (unsigned*)(ws + off); off += 256;
  float* KqT = (float*)(ws + off); off += (size_t)N_KV * D_MODEL * 4;   // [256][2048] f32
  float* VqT = (float*)(ws + off); off += (size_t)N_KV * D_MODEL * 4;
  bf16* QinT = (bf16*)(ws + off); off += (size_t)D_FF * D_MODEL * 2;    // [8192][2048]
  // comb region; QoutT overlays it after GEMM1 (comb dead by then)
  bf16* combHi = (bf16*)(ws + off);
  bf16* QoutT = (bf16*)(ws + off);
  off += (size_t)D_MODEL * D_FF * 2;  // 33.5 MB ([2048][8192])
  bf16* hidHi = (bf16*)(ws + off); off += (size_t)M_ROWS * D_FF * 2;    // 67 MB

  hipMemsetAsync(maxb, 0, 16, stream);
  hipMemsetAsync(out, 0, (size_t)M_ROWS * D_MODEL * 4, stream);  // split-K atomic target
  maxabs4_kernel<<<dim3(512, 4), 256, 0, stream>>>(
      (const float4*)W_K, (D_MODEL * N_KV) / 4, (const float4*)W_V, (D_MODEL * N_KV) / 4,
      (const float4*)W_in, (D_MODEL * D_FF) / 4, (const float4*)W_out, (D_FF * D_MODEL) / 4,
      maxb);

  quantT_f32<<<dim3(N_KV / 64, D_MODEL / 64), 256, 0, stream>>>(W_K, KqT, D_MODEL, N_KV, maxb + 0);
  quantT_f32<<<dim3(N_KV / 64, D_MODEL / 64), 256, 0, stream>>>(W_V, VqT, D_MODEL, N_KV, maxb + 1);
  quantT_bf16<<<dim3(D_FF / 64, D_MODEL / 64), 256, 0, stream>>>(W_in, QinT, D_MODEL, D_FF, maxb + 2);

  attn_kernel<<<M_ROWS, 256, 0, stream>>>(x, idx, KqT, VqT, combHi);

  gemm8<D_MODEL, false, bf16><<<dim3(D_FF / 256, M_ROWS / 256), 512, 0, stream>>>(
      combHi, QinT, maxb + 2, hidHi, D_FF);

  quantT_bf16<<<dim3(D_MODEL / 64, D_FF / 64), 256, 0, stream>>>(W_out, QoutT, D_FF, D_MODEL, maxb + 3);

  gemm8<D_FF, true, float><<<dim3(D_MODEL / 256, M_ROWS / 256, 2), 512, 0, stream>>>(
      hidHi, QoutT, maxb + 3, out, D_MODEL);
}

// Round 10
// 388.590 us; speedup vs baseline: 1.2128x; 1.1949x over previous
//
#include <hip/hip_runtime.h>
#include <hip/hip_bf16.h>

// Problem constants
#define D_MODEL 2048
#define D_FF    8192
#define N_KV    256
#define S_TOP   16
#define M_ROWS  4096   // B*T = 4*1024

typedef __attribute__((ext_vector_type(8))) short bf16x8;   // 8 bf16 (4 VGPRs)
typedef __attribute__((ext_vector_type(4))) float f32x4;
typedef __hip_bfloat16 bf16;

typedef const __attribute__((address_space(1))) unsigned int* gp_t;
typedef __attribute__((address_space(3))) unsigned int* lp_t;

__device__ __forceinline__ void gload16(const void* g, void* l) {
  // async global->LDS, 16B per lane; LDS dest = wave-uniform base + lane*16
  __builtin_amdgcn_global_load_lds((gp_t)g, (lp_t)l, 16, 0, 0);
}

__device__ __forceinline__ float bf2f(short s) {
  return __uint_as_float(((unsigned)(unsigned short)s) << 16);
}

// ---------------- fused max|w| over the 4 weight tensors (blockIdx.y selects tensor) -------
__global__ __launch_bounds__(256) void maxabs4_kernel(const float4* __restrict__ w0, int n0,
                                                      const float4* __restrict__ w1, int n1,
                                                      const float4* __restrict__ w2, int n2,
                                                      const float4* __restrict__ w3, int n3,
                                                      unsigned* __restrict__ out) {
  const float4* w = blockIdx.y == 0 ? w0 : blockIdx.y == 1 ? w1 : blockIdx.y == 2 ? w2 : w3;
  int n4 = blockIdx.y == 0 ? n0 : blockIdx.y == 1 ? n1 : blockIdx.y == 2 ? n2 : n3;
  float m = 0.f;
  for (long i = (long)blockIdx.x * 256 + threadIdx.x; i < n4; i += (long)gridDim.x * 256) {
    float4 v = w[i];
    m = fmaxf(m, fmaxf(fmaxf(fabsf(v.x), fabsf(v.y)), fmaxf(fabsf(v.z), fabsf(v.w))));
  }
#pragma unroll
  for (int o = 32; o; o >>= 1) m = fmaxf(m, __shfl_down(m, o, 64));
  __shared__ float sm[4];
  int lane = threadIdx.x & 63, wid = threadIdx.x >> 6;
  if (lane == 0) sm[wid] = m;
  __syncthreads();
  if (threadIdx.x == 0) {
    float mm = fmaxf(fmaxf(sm[0], sm[1]), fmaxf(sm[2], sm[3]));
    atomicMax(out + blockIdx.y, __float_as_uint(mm));
  }
}

// ---------------- quantize + transpose: in [R][C] f32 -> out [C][R] bf16 INTEGER codes -----
// Codes are exact in bf16 (|q|<=127); dequant scale applied downstream.
__global__ __launch_bounds__(256) void quantT_bf16(const float* __restrict__ in,
                                                   bf16* __restrict__ out, int R, int C,
                                                   const unsigned* __restrict__ maxbits) {
  __shared__ float tile[64][65];
  float scale = 127.f / fmaxf(__uint_as_float(*maxbits), 1e-8f);
  int r0 = blockIdx.y << 6, c0 = blockIdx.x << 6;
  int tx = threadIdx.x & 63, ty = threadIdx.x >> 6;
#pragma unroll
  for (int i = 0; i < 16; ++i) {
    int r = ty + (i << 2);
    float v = in[(long)(r0 + r) * C + c0 + tx];
    tile[r][tx] = fminf(fmaxf(rintf(v * scale), -128.f), 127.f);
  }
  __syncthreads();
#pragma unroll
  for (int i = 0; i < 16; ++i) {
    int c = ty + (i << 2);
    out[(long)(c0 + c) * R + r0 + tx] = __float2bfloat16(tile[tx][c]);
  }
}

// merged K+V variant: blockIdx.z selects tensor (both [2048][256] -> [256][2048])
__global__ __launch_bounds__(256) void quantKV_kernel(const float* __restrict__ WK,
                                                      const float* __restrict__ WV,
                                                      bf16* __restrict__ Kq,
                                                      bf16* __restrict__ Vq,
                                                      const unsigned* __restrict__ maxb) {
  __shared__ float tile[64][65];
  const float* in = blockIdx.z ? WV : WK;
  bf16* out = blockIdx.z ? Vq : Kq;
  float scale = 127.f / fmaxf(__uint_as_float(maxb[blockIdx.z]), 1e-8f);
  int r0 = blockIdx.y << 6, c0 = blockIdx.x << 6;
  int tx = threadIdx.x & 63, ty = threadIdx.x >> 6;
#pragma unroll
  for (int i = 0; i < 16; ++i) {
    int r = ty + (i << 2);
    float v = in[(long)(r0 + r) * N_KV + c0 + tx];
    tile[r][tx] = fminf(fmaxf(rintf(v * scale), -128.f), 127.f);
  }
  __syncthreads();
#pragma unroll
  for (int i = 0; i < 16; ++i) {
    int c = ty + (i << 2);
    out[(long)(c0 + c) * D_MODEL + r0 + tx] = __float2bfloat16(tile[tx][c]);
  }
}

// ---------------- gather-attention: one block per (b,t); bf16 integer-code K/V -------------
// score = (x . Kq_codes) * invK  (scale BEFORE softmax); comb = (sum p*Vq_codes) * invV.
// Thread t owns contiguous d in [8t, 8t+8): float4 x loads, 16B K/V loads, 16B comb store.
__global__ __launch_bounds__(256) void attn_kernel(const float* __restrict__ x,
                                                   const int* __restrict__ idx,
                                                   const bf16* __restrict__ Kq,
                                                   const bf16* __restrict__ Vq,
                                                   const unsigned* __restrict__ maxb,
                                                   bf16* __restrict__ comb) {
  int bt = blockIdx.x;
  const float* xr = x + (long)bt * D_MODEL;
  __shared__ int sidx[S_TOP];
  __shared__ float sred[S_TOP][4];
  __shared__ float sp[S_TOP];
  int t = threadIdx.x, lane = t & 63, wid = t >> 6;
  if (t < S_TOP) sidx[t] = idx[(long)bt * S_TOP + t];
  __syncthreads();
  float invK = fmaxf(__uint_as_float(maxb[0]), 1e-8f) * (1.f / 127.f);
  float invV = fmaxf(__uint_as_float(maxb[1]), 1e-8f) * (1.f / 127.f);
  float4 xa = *(const float4*)(xr + t * 8);
  float4 xb = *(const float4*)(xr + t * 8 + 4);
  float xv[8] = {xa.x, xa.y, xa.z, xa.w, xb.x, xb.y, xb.z, xb.w};
#pragma unroll
  for (int s = 0; s < S_TOP; ++s) {
    bf16x8 kv = *(const bf16x8*)(Kq + (long)sidx[s] * D_MODEL + t * 8);
    float a = 0.f;
#pragma unroll
    for (int j = 0; j < 8; ++j) a += xv[j] * bf2f(kv[j]);
#pragma unroll
    for (int o = 32; o; o >>= 1) a += __shfl_down(a, o, 64);
    if (lane == 0) sred[s][wid] = a;
  }
  __syncthreads();
  if (t < S_TOP) {
    float sc = (sred[t][0] + sred[t][1] + sred[t][2] + sred[t][3]) * invK;
    float mx = sc;
#pragma unroll
    for (int o = 8; o; o >>= 1) mx = fmaxf(mx, __shfl_xor(mx, o, 16));
    float e = __expf(sc - mx);
    float su = e;
#pragma unroll
    for (int o = 8; o; o >>= 1) su += __shfl_xor(su, o, 16);
    sp[t] = e / su;
  }
  __syncthreads();
  float p[S_TOP];
#pragma unroll
  for (int s = 0; s < S_TOP; ++s) p[s] = sp[s];
  float c[8] = {};
#pragma unroll
  for (int s = 0; s < S_TOP; ++s) {
    bf16x8 vv = *(const bf16x8*)(Vq + (long)sidx[s] * D_MODEL + t * 8);
#pragma unroll
    for (int j = 0; j < 8; ++j) c[j] += p[s] * bf2f(vv[j]);
  }
  bf16x8 ov;
#pragma unroll
  for (int j = 0; j < 8; ++j) {
    union { bf16 b; short s; } u;
    u.b = __float2bfloat16(c[j] * invV);
    ov[j] = u.s;
  }
  *(bf16x8*)(comb + (long)bt * D_MODEL + t * 8) = ov;
}

// ---------------- 256x256 8-wave deep-pipelined GEMM (r6 structure: counted vmcnt) ---------
// C[M][N] = A @ B^T * (max/127).  A: [M][KT] bf16 acts, B: [N][KT] bf16 integer codes.
// BK=64, ping-pong LDS. Staging FIFO per tile (in order): A0,A1 (phase1) B0,B1 (phase2).
// Waits are COUNTED (never drain in-loop):
//   top:      vmcnt(2)  -> tile j's A0,A1,B0 landed (B1 may fly);  s_barrier
//   phase1:   ds aF[0-3](A0), bF[0-1](B0); stage A0',A1'; MFMA x16
//   mid:      vmcnt(4) [last iter: 0] -> tile j's B1 landed;       s_barrier
//   phase2:   ds bF[2-3](B1); stage B0',B1'; MFMA x16
//   phase3:   ds aF[4-7](A1); MFMA x16        (A1 covered by top wait)
//   phase4:   MFMA x16
// LDS bank swizzle: byte_col ^= (row&7)<<4 via pre-swizzled global source col + swizzled
// ds_read (both-sides rule); measured conflict-free (r5/r6: SQ_LDS_BANK_CONFLICT = 0).
// SPLITK: gridDim.z=2, halves atomicAdd f32 into zeroed out (2 addends -> deterministic).
template <int KT, bool SPLITK, typename OutT>
__global__ __launch_bounds__(512, 2) void gemm8(const bf16* __restrict__ A,
                                                const bf16* __restrict__ B,
                                                const unsigned* maxbits,
                                                OutT* __restrict__ out, int Ntot) {
  __shared__ char lds[131072];  // A: [2][256][64] @0 (64KB), B: same @65536
  const int t = threadIdx.x, lane = t & 63, wid = t >> 6;
  const int wr = wid >> 2, wc = wid & 3;            // wave grid 2M x 4N
  // bijective XCD swizzle over (x,y); nwg % 8 == 0 for all our grids
  const int gx = gridDim.x, nwg = gx * gridDim.y;
  const int bid = blockIdx.y * gx + blockIdx.x;
  const int swz = (bid & 7) * (nwg >> 3) + (bid >> 3);
  const long m0 = (long)(swz / gx) << 8;
  const long n0 = (long)(swz % gx) << 8;
  const int NT = (SPLITK ? KT / 2 : KT) / 64;
  const bf16* gA = A + m0 * KT + (SPLITK ? blockIdx.z * (KT / 2) : 0);
  const bf16* gB = B + n0 * KT + (SPLITK ? blockIdx.z * (KT / 2) : 0);

  // staging: thread t covers row srow=t>>3, 16B slot (t&7); source col inverse-swizzled
  const int srow = t >> 3;                           // 0..63 per gload round
  const int gcol = ((t & 7) ^ (srow & 7)) << 3;      // elements (bytes>>1)
  // frag reads: byte col ^= (row&7)<<4; row&7 == lane&7 (all row bases are mult of 16)
  const int xr = (lane & 7) << 4;
  const int arow = lane & 15;
  const int kcolb = (lane >> 4) << 4;                // 0,16,32,48 bytes

  f32x4 acc[8][4] = {};

#define STAGE(mat, h, j, c)                                                          \
  {                                                                                  \
    const bf16* _g = (mat ? gB : gA) + (long)((h)*128) * KT + (long)(j)*64 + gcol;   \
    char* _l = lds + (mat)*65536 + (c)*32768 + (h)*16384;                            \
    gload16(_g + (long)srow * KT, _l + (t << 4));                                    \
    gload16(_g + (long)(64 + srow) * KT, _l + 8192 + (t << 4));                      \
  }

  // prologue: tile 0 -> buf 0, FIFO order A0,A1,B0,B1
  STAGE(0, 0, 0, 0) STAGE(0, 1, 0, 0) STAGE(1, 0, 0, 0) STAGE(1, 1, 0, 0)

  bf16x8 aF[4][2], bF[4][2];

  for (int j = 0; j < NT; ++j) {
    const int c = j & 1;
    const char* lA = lds + c * 32768;
    const char* lB = lds + 65536 + c * 32768;
    asm volatile("s_waitcnt vmcnt(2)" ::: "memory");  // tile j A0,A1,B0 landed (own loads)
    __builtin_amdgcn_s_barrier();                     // -> block-wide
    // ---- phase 1: A[m0..3] (A0) + B[n0..1] (B0); stage next A
#pragma unroll
    for (int m = 0; m < 4; ++m)
#pragma unroll
      for (int ks = 0; ks < 2; ++ks)
        aF[m][ks] = *(const bf16x8*)(lA + (wr * 128 + m * 16 + arow) * 128 +
                                     ((ks * 64 + kcolb) ^ xr));
#pragma unroll
    for (int n = 0; n < 2; ++n)
#pragma unroll
      for (int ks = 0; ks < 2; ++ks)
        bF[n][ks] = *(const bf16x8*)(lB + (wc * 64 + n * 16 + arow) * 128 +
                                     ((ks * 64 + kcolb) ^ xr));
    if (j + 1 < NT) { STAGE(0, 0, j + 1, c ^ 1) STAGE(0, 1, j + 1, c ^ 1) }
    __builtin_amdgcn_s_setprio(1);
#pragma unroll
    for (int m = 0; m < 4; ++m)
#pragma unroll
      for (int n = 0; n < 2; ++n)
#pragma unroll
        for (int ks = 0; ks < 2; ++ks)
          acc[m][n] = __builtin_amdgcn_mfma_f32_16x16x32_bf16(aF[m][ks], bF[n][ks], acc[m][n], 0, 0, 0);
    __builtin_amdgcn_s_setprio(0);
    // ---- mid wait: tile j's B1 landed (outstanding: B1_j + 4 A'-loads just staged)
    if (j + 1 < NT) { asm volatile("s_waitcnt vmcnt(4)" ::: "memory"); }
    else           { asm volatile("s_waitcnt vmcnt(0)" ::: "memory"); }
    __builtin_amdgcn_s_barrier();
    // ---- phase 2: B[n2..3] (B1); stage next B
#pragma unroll
    for (int n = 0; n < 2; ++n)
#pragma unroll
      for (int ks = 0; ks < 2; ++ks)
        bF[2 + n][ks] = *(const bf16x8*)(lB + (wc * 64 + (2 + n) * 16 + arow) * 128 +
                                         ((ks * 64 + kcolb) ^ xr));
    if (j + 1 < NT) { STAGE(1, 0, j + 1, c ^ 1) STAGE(1, 1, j + 1, c ^ 1) }
    __builtin_amdgcn_s_setprio(1);
#pragma unroll
    for (int m = 0; m < 4; ++m)
#pragma unroll
      for (int n = 0; n < 2; ++n)
#pragma unroll
        for (int ks = 0; ks < 2; ++ks)
          acc[m][2 + n] = __builtin_amdgcn_mfma_f32_16x16x32_bf16(aF[m][ks], bF[2 + n][ks], acc[m][2 + n], 0, 0, 0);
    __builtin_amdgcn_s_setprio(0);
    // ---- phase 3: A[m4..7] (A1; landed per top wait)
#pragma unroll
    for (int m = 0; m < 4; ++m)
#pragma unroll
      for (int ks = 0; ks < 2; ++ks)
        aF[m][ks] = *(const bf16x8*)(lA + (wr * 128 + (4 + m) * 16 + arow) * 128 +
                                     ((ks * 64 + kcolb) ^ xr));
    __builtin_amdgcn_s_setprio(1);
#pragma unroll
    for (int m = 0; m < 4; ++m)
#pragma unroll
      for (int n = 0; n < 2; ++n)
#pragma unroll
        for (int ks = 0; ks < 2; ++ks)
          acc[4 + m][n] = __builtin_amdgcn_mfma_f32_16x16x32_bf16(aF[m][ks], bF[n][ks], acc[4 + m][n], 0, 0, 0);
    __builtin_amdgcn_s_setprio(0);
    // ---- phase 4
    __builtin_amdgcn_s_setprio(1);
#pragma unroll
    for (int m = 0; m < 4; ++m)
#pragma unroll
      for (int n = 0; n < 2; ++n)
#pragma unroll
        for (int ks = 0; ks < 2; ++ks)
          acc[4 + m][2 + n] = __builtin_amdgcn_mfma_f32_16x16x32_bf16(aF[m][ks], bF[2 + n][ks], acc[4 + m][2 + n], 0, 0, 0);
    __builtin_amdgcn_s_setprio(0);
  }
#undef STAGE

  // volatile AFTER the loop: keeps this VMEM op out of the pipelined region
  float inv = fmaxf(__uint_as_float(*(volatile const unsigned*)maxbits), 1e-8f) * (1.f / 127.f);
#pragma unroll
  for (int m = 0; m < 8; ++m)
#pragma unroll
    for (int n = 0; n < 4; ++n)
#pragma unroll
      for (int r = 0; r < 4; ++r) {
        long row = m0 + wr * 128 + m * 16 + ((lane >> 4) << 2) + r;  // C/D: row=(lane>>4)*4+reg
        long col = n0 + wc * 64 + n * 16 + (lane & 15);              //      col=lane&15
        float h = acc[m][n][r] * inv;
        if constexpr (SPLITK)
          atomicAdd(&out[row * Ntot + col], h);
        else if constexpr (__is_same(OutT, float))
          out[row * Ntot + col] = h;
        else
          out[row * Ntot + col] = __float2bfloat16(h);
      }
}

extern "C" void kernel_launch(void* const* d_in, const int* in_sizes, int n_in, void* d_out,
                              int out_size, void* d_ws, size_t ws_size, hipStream_t stream) {
  const float* x = (const float*)d_in[0];
  const int* idx = (const int*)d_in[1];
  const float* W_K = (const float*)d_in[2];
  const float* W_V = (const float*)d_in[3];
  const float* W_in = (const float*)d_in[4];
  const float* W_out = (const float*)d_in[5];
  float* out = (float*)d_out;  // reference output dtype is float32

  char* ws = (char*)d_ws;
  size_t off = 0;
  unsigned* maxb = (unsigned*)(ws + off); off += 256;
  bf16* KqT = (bf16*)(ws + off); off += (size_t)N_KV * D_MODEL * 2;     // [256][2048] bf16 codes
  bf16* VqT = (bf16*)(ws + off); off += (size_t)N_KV * D_MODEL * 2;
  bf16* QinT = (bf16*)(ws + off); off += (size_t)D_FF * D_MODEL * 2;    // [8192][2048]
  // comb region; QoutT overlays it after GEMM1 (comb dead by then)
  bf16* combHi = (bf16*)(ws + off);
  bf16* QoutT = (bf16*)(ws + off);
  off += (size_t)D_MODEL * D_FF * 2;  // 33.5 MB ([2048][8192])
  bf16* hidHi = (bf16*)(ws + off); off += (size_t)M_ROWS * D_FF * 2;    // 67 MB

  hipMemsetAsync(maxb, 0, 16, stream);
  hipMemsetAsync(out, 0, (size_t)M_ROWS * D_MODEL * 4, stream);  // split-K atomic target
  maxabs4_kernel<<<dim3(512, 4), 256, 0, stream>>>(
      (const float4*)W_K, (D_MODEL * N_KV) / 4, (const float4*)W_V, (D_MODEL * N_KV) / 4,
      (const float4*)W_in, (D_MODEL * D_FF) / 4, (const float4*)W_out, (D_FF * D_MODEL) / 4,
      maxb);

  quantKV_kernel<<<dim3(N_KV / 64, D_MODEL / 64, 2), 256, 0, stream>>>(W_K, W_V, KqT, VqT, maxb);
  quantT_bf16<<<dim3(D_FF / 64, D_MODEL / 64), 256, 0, stream>>>(W_in, QinT, D_MODEL, D_FF, maxb + 2);

  attn_kernel<<<M_ROWS, 256, 0, stream>>>(x, idx, KqT, VqT, maxb, combHi);

  gemm8<D_MODEL, false, bf16><<<dim3(D_FF / 256, M_ROWS / 256), 512, 0, stream>>>(
      combHi, QinT, maxb + 2, hidHi, D_FF);

  quantT_bf16<<<dim3(D_MODEL / 64, D_FF / 64), 256, 0, stream>>>(W_out, QoutT, D_FF, D_MODEL, maxb + 3);

  gemm8<D_FF, true, float><<<dim3(D_MODEL / 256, M_ROWS / 256, 2), 512, 0, stream>>>(
      hidHi, QoutT, maxb + 3, out, D_MODEL);
}